// Round 12
// baseline (303.822 us; speedup 1.0000x reference)
//
#include <hip/hip_runtime.h>
#include <hip/hip_bf16.h>

#define NEG_SLOPE 0.2f
#define LOG2E 1.4426950408889634f
#define MAXDEG 64   // Poisson(10): P(deg>64) ~ 1e-35 -> dense slots are safe

typedef __bf16 v8bf __attribute__((ext_vector_type(8)));
typedef float  v4f  __attribute__((ext_vector_type(4)));

static __device__ __forceinline__ unsigned short f2b(float f) {
    unsigned u = __builtin_bit_cast(unsigned, f);
    u += 0x7FFFu + ((u >> 16) & 1u);           // RNE to bf16
    return (unsigned short)(u >> 16);
}
static __device__ __forceinline__ void b2f2(unsigned u, float& lo, float& hi) {
    lo = __builtin_bit_cast(float, u << 16);
    hi = __builtin_bit_cast(float, u & 0xFFFF0000u);
}
static __device__ __forceinline__ void unpack8(uint4 u, float* f) {
    b2f2(u.x, f[0], f[1]); b2f2(u.y, f[2], f[3]);
    b2f2(u.z, f[4], f[5]); b2f2(u.w, f[6], f[7]);
}
static __device__ __forceinline__ int atomIncI(int* p) {
    return __hip_atomic_fetch_add(p, 1, __ATOMIC_RELAXED, __HIP_MEMORY_SCOPE_AGENT);
}

// ---------------------------------------------------------------------------
// kA: weight-pack only (counts zeroing moved to hipMemsetAsync).
// Wt layout: [feat(384)][k(128)] bf16 so MFMA A-frags are contiguous 16B.
// ---------------------------------------------------------------------------
__global__ __launch_bounds__(256) void kA_prep(
    const float* __restrict__ Wl, const float* __restrict__ Wr,
    const float* __restrict__ Ws, unsigned short* __restrict__ Wt)
{
    int t = blockIdx.x * 256 + threadIdx.x;     // < 49152
    int nn = t >> 7, k = t & 127;
    const float* W = (nn < 128) ? Wl : ((nn < 256) ? Wr : Ws);
    Wt[t] = f2b(W[k * 128 + (nn & 127)]);
}

// ---------------------------------------------------------------------------
// kB: fused dense-slot CSR build (blocks < KB_HB) + node GEMM (rest).
// Build: r = counts[dst]++ ; dense[dst*64+r] = src. 2x unrolled so the two
//   load->atomic->store chains pipeline per thread (R11: single chain).
// GEMM: 32 nodes/block, 4 waves; wave w owns feats [96w,96w+96); 48 acc
//   regs/wave; LDS staging [32][136] + aliased out tile [3][32][132];
//   coalesced 3x8KB stores (R9-verified).
// ---------------------------------------------------------------------------
#define KB_HB 512

__global__ __launch_bounds__(256) void kB_build_gemm(
    const int* __restrict__ ei, int E,
    int* __restrict__ counts, int* __restrict__ dense,
    const float* __restrict__ x, const float* __restrict__ tf,
    const unsigned short* __restrict__ Wt,
    const float* __restrict__ bg, const float* __restrict__ bs,
    unsigned short* __restrict__ xl_b, unsigned short* __restrict__ xr_b,
    unsigned short* __restrict__ sk_b, int N)
{
    __shared__ unsigned short lds[12672];       // 25344 B
    const int tid = threadIdx.x;

    if (blockIdx.x < KB_HB) {
        const int stride = KB_HB * 256;
        for (int e = blockIdx.x * 256 + tid; e < E; e += 2 * stride) {
            const int e2 = e + stride;
            const bool v2 = e2 < E;
            int src1 = ei[e];
            int dst1 = ei[E + e];
            int src2 = 0, dst2 = 0;
            if (v2) { src2 = ei[e2]; dst2 = ei[E + e2]; }
            int r1 = atomIncI(&counts[dst1]);
            int r2 = v2 ? atomIncI(&counts[dst2]) : MAXDEG;
            if (r1 < MAXDEG) dense[(size_t)dst1 * MAXDEG + r1] = src1;
            if (r2 < MAXDEG) dense[(size_t)dst2 * MAXDEG + r2] = src2;
        }
        return;
    }

    const int base = ((int)blockIdx.x - KB_HB) * 32;

    // ---- stage 32 node rows (x||tf) into LDS as bf16, rows padded to 136 ----
    #pragma unroll
    for (int t = 0; t < 8; ++t) {
        int idx = tid + t * 256;                 // 0..2015 = 32 rows x 63 float2
        if (idx < 2016) {
            int row = idx / 63;
            int c = idx - row * 63;
            int gr = base + row; if (gr >= N) gr = N - 1;
            float2 v = *reinterpret_cast<const float2*>(x + (size_t)gr * 126 + 2 * c);
            unsigned u = (unsigned)f2b(v.x) | ((unsigned)f2b(v.y) << 16);
            *reinterpret_cast<unsigned*>(&lds[row * 136 + 2 * c]) = u;
        }
    }
    if (tid < 32) {
        int gr = base + tid; if (gr >= N) gr = N - 1;
        float2 v = *reinterpret_cast<const float2*>(tf + (size_t)gr * 2);
        unsigned u = (unsigned)f2b(v.x) | ((unsigned)f2b(v.y) << 16);
        *reinterpret_cast<unsigned*>(&lds[tid * 136 + 126]) = u;
    }
    __syncthreads();

    const int wv = tid >> 6;                     // wave 0..3: feats 96w..96w+95
    const int lane = tid & 63;
    const int nidx = lane & 15, quad = lane >> 4;
    const int fbase = wv * 96;

    v4f acc[6][2];                               // [feat-frag][node-frag]
    #pragma unroll
    for (int a = 0; a < 6; ++a)
        #pragma unroll
        for (int b = 0; b < 2; ++b) acc[a][b] = 0.0f;

    #pragma unroll
    for (int ks = 0; ks < 4; ++ks) {
        v8bf bfr[2];
        #pragma unroll
        for (int nf = 0; nf < 2; ++nf)
            bfr[nf] = *reinterpret_cast<const v8bf*>(
                &lds[(nf * 16 + nidx) * 136 + ks * 32 + quad * 8]);
        #pragma unroll
        for (int ft = 0; ft < 6; ++ft) {
            v8bf afr = *reinterpret_cast<const v8bf*>(
                Wt + (size_t)(fbase + ft * 16 + nidx) * 128 + ks * 32 + quad * 8);
            #pragma unroll
            for (int nf = 0; nf < 2; ++nf)
                acc[ft][nf] = __builtin_amdgcn_mfma_f32_16x16x32_bf16(
                    afr, bfr[nf], acc[ft][nf], 0, 0, 0);
        }
    }

    __syncthreads();                             // staging reads done; re-use LDS

    // ---- deposit acc (bias applied) into out tile [arr][node][col pad 132] ----
    #pragma unroll
    for (int ft = 0; ft < 6; ++ft) {
        const int f = fbase + ft * 16;
        const int arr = f >> 7;
        const int colb = (f & 127) + quad * 4;
        float b0 = 0.0f, b1 = 0.0f, b2 = 0.0f, b3 = 0.0f;
        if (arr == 2) {                           // sk gets bs + bias_gat
            float4 v1 = *reinterpret_cast<const float4*>(bs + (f & 127) + quad * 4);
            float4 v2 = *reinterpret_cast<const float4*>(bg + (f & 127) + quad * 4);
            b0 = v1.x + v2.x; b1 = v1.y + v2.y; b2 = v1.z + v2.z; b3 = v1.w + v2.w;
        }
        #pragma unroll
        for (int nf = 0; nf < 2; ++nf) {
            const int nloc = nf * 16 + nidx;
            v4f v = acc[ft][nf];
            uint2 p;
            p.x = (unsigned)f2b(v[0] + b0) | ((unsigned)f2b(v[1] + b1) << 16);
            p.y = (unsigned)f2b(v[2] + b2) | ((unsigned)f2b(v[3] + b3) << 16);
            *reinterpret_cast<uint2*>(&lds[arr * 4224 + nloc * 132 + colb]) = p;
        }
    }
    __syncthreads();

    // ---- cooperative coalesced store: 3 arrays x 512 uint4 (8KB contiguous) --
    #pragma unroll
    for (int it = 0; it < 6; ++it) {
        int i = tid + it * 256;                  // 0..1535
        int arr = i >> 9;
        int idx = i & 511;
        int nloc = idx >> 4;
        int colh = (idx & 15) * 8;
        int node = base + nloc;
        if (node < N) {
            uint4 v = *reinterpret_cast<const uint4*>(&lds[arr * 4224 + nloc * 132 + colh]);
            unsigned short* dp = (arr == 0) ? xl_b : ((arr == 1) ? xr_b : sk_b);
            *reinterpret_cast<uint4*>(dp + (size_t)node * 128 + colh) = v;
        }
    }
}

// ---------------------------------------------------------------------------
// k2: fused segment-reduce + finalize with a 4-DEEP GATHER RING.
// One wave per node; 4 edge-slots of 16 lanes; lane j covers cols 8j..8j+7.
// All src loads + xl gathers for 4 iterations (16 slots >= typical deg+1)
// are issued up front; the loop computes iter `it` while refilling slot
// it&3 for it+4. Out-of-range slots clamp to src=node (safe address, e
// masked to 0). Typical node: ONE latency exposure instead of three (R11
// post-mortem: k2 is gather-latency bound, ALU floor ~12us).
// ---------------------------------------------------------------------------
__global__ __launch_bounds__(256, 6) void k2_aggfin(
    const int* __restrict__ counts, const int* __restrict__ dense,
    const unsigned short* __restrict__ xl_b,
    const unsigned short* __restrict__ xr_b,
    const unsigned short* __restrict__ sk_b,
    const float* __restrict__ att,
    const float* __restrict__ Wo, const float* __restrict__ bo,
    float* __restrict__ out, int N)
{
    const int node = (int)((blockIdx.x * (size_t)blockDim.x + threadIdx.x) >> 6);
    const int lane = threadIdx.x & 63;
    if (node >= N) return;
    const int j = lane & 15;                    // col-lane within edge slot
    const int g = lane >> 4;                    // edge slot 0..3
    const int cb = j * 8;                       // first col of this lane

    float4 a0 = *reinterpret_cast<const float4*>(att + cb);
    float4 a1 = *reinterpret_cast<const float4*>(att + cb + 4);
    float av[8] = {a0.x * LOG2E, a0.y * LOG2E, a0.z * LOG2E, a0.w * LOG2E,
                   a1.x * LOG2E, a1.y * LOG2E, a1.z * LOG2E, a1.w * LOG2E};
    float xr[8];
    unpack8(*reinterpret_cast<const uint4*>(xr_b + (size_t)node * 128 + cb), xr);

    float acc[8];
    #pragma unroll
    for (int c = 0; c < 8; ++c) acc[c] = 0.0f;
    float den = 0.0f;

    int cnt = counts[node]; if (cnt > MAXDEG) cnt = MAXDEG;
    const int total = cnt + 1;                  // + self-loop (logical item 0)
    const int* seg = dense + (size_t)node * MAXDEG - 1;   // seg[ic], ic>=1

    auto loadsrc = [&](int slotbase) -> int {
        int ii = slotbase + g;
        int ic = (ii > 0 && ii < total) ? ii : 0;
        return (ic == 0) ? node : seg[ic];
    };
    auto gather = [&](int src) -> uint4 {
        return *reinterpret_cast<const uint4*>(xl_b + (size_t)src * 128 + cb);
    };

    // fill the 4-deep ring: 4 src loads + 4 gathers in flight per lane
    int   s[4];
    uint4 u[4];
    #pragma unroll
    for (int p = 0; p < 4; ++p) s[p] = loadsrc(p * 4);
    #pragma unroll
    for (int p = 0; p < 4; ++p) u[p] = gather(s[p]);

    const int iters = (total + 3) >> 2;
    for (int it = 0; it < iters; ++it) {
        const int slot = it & 3;
        uint4 cur = u[slot];
        // refill this slot for iteration it+4 (safe clamped addresses)
        s[slot] = loadsrc((it + 4) * 4);
        u[slot] = gather(s[slot]);

        bool valid = (it * 4 + g) < total;
        float xl[8];
        unpack8(cur, xl);
        float t = 0.0f;
        #pragma unroll
        for (int c = 0; c < 8; ++c) {
            float m = xl[c] + xr[c];
            float l = fmaxf(m, NEG_SLOPE * m);  // leaky relu
            t = fmaf(l, av[c], t);
        }
        t += __shfl_xor(t, 1, 64);              // close 16-col head dot
        float e = valid ? exp2f(t) : 0.0f;
        #pragma unroll
        for (int c = 0; c < 8; ++c) acc[c] = fmaf(e, xl[c], acc[c]);
        den += e;
    }

    // merge the 4 edge slots (lanes +-16, +-32 hold same cols)
    #pragma unroll
    for (int c = 0; c < 8; ++c) {
        acc[c] += __shfl_xor(acc[c], 16, 64);
        acc[c] += __shfl_xor(acc[c], 32, 64);
    }
    den += __shfl_xor(den, 16, 64);
    den += __shfl_xor(den, 32, 64);

    float rd = 1.0f / (den + 1e-16f);
    float sk[8];
    unpack8(*reinterpret_cast<const uint4*>(sk_b + (size_t)node * 128 + cb), sk);
    float4 w0 = *reinterpret_cast<const float4*>(Wo + cb);
    float4 w1 = *reinterpret_cast<const float4*>(Wo + cb + 4);
    float wv[8] = {w0.x, w0.y, w0.z, w0.w, w1.x, w1.y, w1.z, w1.w};
    float s2 = 0.0f;
    #pragma unroll
    for (int c = 0; c < 8; ++c) {
        float gg = fmaf(acc[c], rd, sk[c]);
        float el = gg > 0.0f ? gg : (exp2f(gg * LOG2E) - 1.0f);  // elu
        s2 = fmaf(el, wv[c], s2);
    }
    s2 += __shfl_xor(s2, 1, 64);
    s2 += __shfl_xor(s2, 2, 64);
    s2 += __shfl_xor(s2, 4, 64);
    s2 += __shfl_xor(s2, 8, 64);
    if (lane == 0) {
        float z = s2 + bo[0];
        out[node] = 1.0f / (1.0f + exp2f(-z * LOG2E));
    }
}

// ---------------------------------------------------------------------------
extern "C" void kernel_launch(void* const* d_in, const int* in_sizes, int n_in,
                              void* d_out, int out_size, void* d_ws, size_t ws_size,
                              hipStream_t stream) {
    const float* x   = (const float*)d_in[0];
    const float* tf  = (const float*)d_in[1];
    const int*   ei  = (const int*)  d_in[2];
    const float* Wl  = (const float*)d_in[3];
    const float* Wr  = (const float*)d_in[4];
    const float* att = (const float*)d_in[5];
    const float* bg  = (const float*)d_in[6];
    const float* Ws  = (const float*)d_in[7];
    const float* bs  = (const float*)d_in[8];
    const float* Wo  = (const float*)d_in[9];
    const float* bo  = (const float*)d_in[10];
    float* out = (float*)d_out;

    const int N = in_sizes[0] / 126;
    const int E = in_sizes[2] / 2;

    char* ws = (char*)d_ws;
    unsigned short* Wt   = (unsigned short*)ws; ws += (size_t)384 * 128 * 2;
    unsigned short* xl_b = (unsigned short*)ws; ws += (size_t)N * 128 * 2;
    unsigned short* xr_b = (unsigned short*)ws; ws += (size_t)N * 128 * 2;
    unsigned short* sk_b = (unsigned short*)ws; ws += (size_t)N * 128 * 2;
    int* counts = (int*)ws; ws += (size_t)N * 4;
    int* dense  = (int*)ws; ws += (size_t)N * MAXDEG * 4;   // ~25.6 MB, no zeroing

    // 1: zero counts (graph-capturable) + weight pack
    hipMemsetAsync(counts, 0, (size_t)N * 4, stream);
    hipLaunchKernelGGL(kA_prep, dim3(192), dim3(256), 0, stream, Wl, Wr, Ws, Wt);
    // 2: dense-slot CSR build (atomic-bound) fused with node GEMM (overlap)
    const int GB = (N + 31) / 32;
    hipLaunchKernelGGL(kB_build_gemm, dim3(KB_HB + GB), dim3(256), 0, stream,
                       ei, E, counts, dense, x, tf, Wt, bg, bs,
                       xl_b, xr_b, sk_b, N);
    // 3: segment-reduce + finalize (4-deep gather ring)
    hipLaunchKernelGGL(k2_aggfin, dim3((N + 3) / 4), dim3(256), 0, stream,
                       counts, dense, xl_b, xr_b, sk_b, att, Wo, bo, out, N);
}

// Round 13
// 275.295 us; speedup vs baseline: 1.1036x; 1.1036x over previous
//
#include <hip/hip_runtime.h>
#include <hip/hip_bf16.h>

#define NEG_SLOPE 0.2f
#define LOG2E 1.4426950408889634f
#define MAXDEG 64   // Poisson(10): P(deg>64) ~ 1e-35 -> dense slots are safe

typedef __bf16 v8bf __attribute__((ext_vector_type(8)));
typedef float  v4f  __attribute__((ext_vector_type(4)));

static __device__ __forceinline__ unsigned short f2b(float f) {
    unsigned u = __builtin_bit_cast(unsigned, f);
    u += 0x7FFFu + ((u >> 16) & 1u);           // RNE to bf16
    return (unsigned short)(u >> 16);
}
static __device__ __forceinline__ void b2f2(unsigned u, float& lo, float& hi) {
    lo = __builtin_bit_cast(float, u << 16);
    hi = __builtin_bit_cast(float, u & 0xFFFF0000u);
}
static __device__ __forceinline__ void unpack8(uint4 u, float* f) {
    b2f2(u.x, f[0], f[1]); b2f2(u.y, f[2], f[3]);
    b2f2(u.z, f[4], f[5]); b2f2(u.w, f[6], f[7]);
}
static __device__ __forceinline__ int atomIncI(int* p) {
    return __hip_atomic_fetch_add(p, 1, __ATOMIC_RELAXED, __HIP_MEMORY_SCOPE_AGENT);
}

// ---------------------------------------------------------------------------
// kA: weight-pack only (counts zeroing via hipMemsetAsync).
// Wt layout: [feat(384)][k(128)] bf16 so MFMA A-frags are contiguous 16B.
// ---------------------------------------------------------------------------
__global__ __launch_bounds__(256) void kA_prep(
    const float* __restrict__ Wl, const float* __restrict__ Wr,
    const float* __restrict__ Ws, unsigned short* __restrict__ Wt)
{
    int t = blockIdx.x * 256 + threadIdx.x;     // < 49152
    int nn = t >> 7, k = t & 127;
    const float* W = (nn < 128) ? Wl : ((nn < 256) ? Wr : Ws);
    Wt[t] = f2b(W[k * 128 + (nn & 127)]);
}

// ---------------------------------------------------------------------------
// kB: fused dense-slot CSR build (blocks < KB_HB) + node GEMM (rest).
// Build: r = counts[dst]++ ; dense[dst*64+r] = src; 2x unrolled chains
//   (R12: 130 -> 117us).
// GEMM: 32 nodes/block, 4 waves; wave w owns feats [96w,96w+96); 48 acc
//   regs/wave; LDS staging [32][136] + aliased out tile [3][32][132];
//   coalesced 3x8KB stores (R9-verified).
// ---------------------------------------------------------------------------
#define KB_HB 512

__global__ __launch_bounds__(256) void kB_build_gemm(
    const int* __restrict__ ei, int E,
    int* __restrict__ counts, int* __restrict__ dense,
    const float* __restrict__ x, const float* __restrict__ tf,
    const unsigned short* __restrict__ Wt,
    const float* __restrict__ bg, const float* __restrict__ bs,
    unsigned short* __restrict__ xl_b, unsigned short* __restrict__ xr_b,
    unsigned short* __restrict__ sk_b, int N)
{
    __shared__ unsigned short lds[12672];       // 25344 B
    const int tid = threadIdx.x;

    if (blockIdx.x < KB_HB) {
        const int stride = KB_HB * 256;
        for (int e = blockIdx.x * 256 + tid; e < E; e += 2 * stride) {
            const int e2 = e + stride;
            const bool v2 = e2 < E;
            int src1 = ei[e];
            int dst1 = ei[E + e];
            int src2 = 0, dst2 = 0;
            if (v2) { src2 = ei[e2]; dst2 = ei[E + e2]; }
            int r1 = atomIncI(&counts[dst1]);
            int r2 = v2 ? atomIncI(&counts[dst2]) : MAXDEG;
            if (r1 < MAXDEG) dense[(size_t)dst1 * MAXDEG + r1] = src1;
            if (r2 < MAXDEG) dense[(size_t)dst2 * MAXDEG + r2] = src2;
        }
        return;
    }

    const int base = ((int)blockIdx.x - KB_HB) * 32;

    // ---- stage 32 node rows (x||tf) into LDS as bf16, rows padded to 136 ----
    #pragma unroll
    for (int t = 0; t < 8; ++t) {
        int idx = tid + t * 256;                 // 0..2015 = 32 rows x 63 float2
        if (idx < 2016) {
            int row = idx / 63;
            int c = idx - row * 63;
            int gr = base + row; if (gr >= N) gr = N - 1;
            float2 v = *reinterpret_cast<const float2*>(x + (size_t)gr * 126 + 2 * c);
            unsigned u = (unsigned)f2b(v.x) | ((unsigned)f2b(v.y) << 16);
            *reinterpret_cast<unsigned*>(&lds[row * 136 + 2 * c]) = u;
        }
    }
    if (tid < 32) {
        int gr = base + tid; if (gr >= N) gr = N - 1;
        float2 v = *reinterpret_cast<const float2*>(tf + (size_t)gr * 2);
        unsigned u = (unsigned)f2b(v.x) | ((unsigned)f2b(v.y) << 16);
        *reinterpret_cast<unsigned*>(&lds[tid * 136 + 126]) = u;
    }
    __syncthreads();

    const int wv = tid >> 6;                     // wave 0..3: feats 96w..96w+95
    const int lane = tid & 63;
    const int nidx = lane & 15, quad = lane >> 4;
    const int fbase = wv * 96;

    v4f acc[6][2];                               // [feat-frag][node-frag]
    #pragma unroll
    for (int a = 0; a < 6; ++a)
        #pragma unroll
        for (int b = 0; b < 2; ++b) acc[a][b] = 0.0f;

    #pragma unroll
    for (int ks = 0; ks < 4; ++ks) {
        v8bf bfr[2];
        #pragma unroll
        for (int nf = 0; nf < 2; ++nf)
            bfr[nf] = *reinterpret_cast<const v8bf*>(
                &lds[(nf * 16 + nidx) * 136 + ks * 32 + quad * 8]);
        #pragma unroll
        for (int ft = 0; ft < 6; ++ft) {
            v8bf afr = *reinterpret_cast<const v8bf*>(
                Wt + (size_t)(fbase + ft * 16 + nidx) * 128 + ks * 32 + quad * 8);
            #pragma unroll
            for (int nf = 0; nf < 2; ++nf)
                acc[ft][nf] = __builtin_amdgcn_mfma_f32_16x16x32_bf16(
                    afr, bfr[nf], acc[ft][nf], 0, 0, 0);
        }
    }

    __syncthreads();                             // staging reads done; re-use LDS

    // ---- deposit acc (bias applied) into out tile [arr][node][col pad 132] ----
    #pragma unroll
    for (int ft = 0; ft < 6; ++ft) {
        const int f = fbase + ft * 16;
        const int arr = f >> 7;
        const int colb = (f & 127) + quad * 4;
        float b0 = 0.0f, b1 = 0.0f, b2 = 0.0f, b3 = 0.0f;
        if (arr == 2) {                           // sk gets bs + bias_gat
            float4 v1 = *reinterpret_cast<const float4*>(bs + (f & 127) + quad * 4);
            float4 v2 = *reinterpret_cast<const float4*>(bg + (f & 127) + quad * 4);
            b0 = v1.x + v2.x; b1 = v1.y + v2.y; b2 = v1.z + v2.z; b3 = v1.w + v2.w;
        }
        #pragma unroll
        for (int nf = 0; nf < 2; ++nf) {
            const int nloc = nf * 16 + nidx;
            v4f v = acc[ft][nf];
            uint2 p;
            p.x = (unsigned)f2b(v[0] + b0) | ((unsigned)f2b(v[1] + b1) << 16);
            p.y = (unsigned)f2b(v[2] + b2) | ((unsigned)f2b(v[3] + b3) << 16);
            *reinterpret_cast<uint2*>(&lds[arr * 4224 + nloc * 132 + colb]) = p;
        }
    }
    __syncthreads();

    // ---- cooperative coalesced store: 3 arrays x 512 uint4 (8KB contiguous) --
    #pragma unroll
    for (int it = 0; it < 6; ++it) {
        int i = tid + it * 256;                  // 0..1535
        int arr = i >> 9;
        int idx = i & 511;
        int nloc = idx >> 4;
        int colh = (idx & 15) * 8;
        int node = base + nloc;
        if (node < N) {
            uint4 v = *reinterpret_cast<const uint4*>(&lds[arr * 4224 + nloc * 132 + colh]);
            unsigned short* dp = (arr == 0) ? xl_b : ((arr == 1) ? xr_b : sk_b);
            *reinterpret_cast<uint4*>(dp + (size_t)node * 128 + colh) = v;
        }
    }
}

// ---------------------------------------------------------------------------
// k2: fused segment-reduce + finalize, 4-deep gather ring with STATIC slot
// indices (R12 lesson: u[it&3] runtime indexing demoted the ring to LDS —
// VGPR=32, LDS_Block=16KB, 21M bank conflicts. Scalar ring vars keep it in
// registers). One wave/node; 4 edge-slots x 16 lanes; lane j = cols 8j..8j+7.
// All branches on `iters` are wave-uniform (one node per wave).
// ---------------------------------------------------------------------------
__global__ __launch_bounds__(256, 6) void k2_aggfin(
    const int* __restrict__ counts, const int* __restrict__ dense,
    const unsigned short* __restrict__ xl_b,
    const unsigned short* __restrict__ xr_b,
    const unsigned short* __restrict__ sk_b,
    const float* __restrict__ att,
    const float* __restrict__ Wo, const float* __restrict__ bo,
    float* __restrict__ out, int N)
{
    const int node = (int)((blockIdx.x * (size_t)blockDim.x + threadIdx.x) >> 6);
    const int lane = threadIdx.x & 63;
    if (node >= N) return;
    const int j = lane & 15;                    // col-lane within edge slot
    const int g = lane >> 4;                    // edge slot 0..3
    const int cb = j * 8;                       // first col of this lane

    float4 a0 = *reinterpret_cast<const float4*>(att + cb);
    float4 a1 = *reinterpret_cast<const float4*>(att + cb + 4);
    float av[8] = {a0.x * LOG2E, a0.y * LOG2E, a0.z * LOG2E, a0.w * LOG2E,
                   a1.x * LOG2E, a1.y * LOG2E, a1.z * LOG2E, a1.w * LOG2E};
    float xr[8];
    unpack8(*reinterpret_cast<const uint4*>(xr_b + (size_t)node * 128 + cb), xr);

    float acc[8];
    #pragma unroll
    for (int c = 0; c < 8; ++c) acc[c] = 0.0f;
    float den = 0.0f;

    int cnt = counts[node]; if (cnt > MAXDEG) cnt = MAXDEG;
    const int total = cnt + 1;                  // + self-loop (logical item 0)
    const int* seg = dense + (size_t)node * MAXDEG - 1;   // seg[ic], ic>=1

    auto loadsrc = [&](int slotbase) -> int {
        int ii = slotbase + g;
        int ic = (ii > 0 && ii < total) ? ii : 0;
        return (ic == 0) ? node : seg[ic];
    };
    auto gather = [&](int src) -> uint4 {
        return *reinterpret_cast<const uint4*>(xl_b + (size_t)src * 128 + cb);
    };
    auto proc = [&](uint4 cur, int it) {
        bool valid = (it * 4 + g) < total;
        float xl[8];
        unpack8(cur, xl);
        float t = 0.0f;
        #pragma unroll
        for (int c = 0; c < 8; ++c) {
            float m = xl[c] + xr[c];
            float l = fmaxf(m, NEG_SLOPE * m);  // leaky relu
            t = fmaf(l, av[c], t);
        }
        t += __shfl_xor(t, 1, 64);              // close 16-col head dot
        float e = valid ? exp2f(t) : 0.0f;
        #pragma unroll
        for (int c = 0; c < 8; ++c) acc[c] = fmaf(e, xl[c], acc[c]);
        den += e;
    };

    // fill the 4-deep ring (scalar vars -> register-resident)
    int   s0 = loadsrc(0),  s1 = loadsrc(4),  s2 = loadsrc(8),  s3 = loadsrc(12);
    uint4 u0 = gather(s0),  u1 = gather(s1),  u2 = gather(s2),  u3 = gather(s3);

    const int iters = (total + 3) >> 2;
    for (int it = 0; it < iters; it += 4) {
        proc(u0, it);
        s0 = loadsrc((it + 4) * 4); u0 = gather(s0);
        if (it + 1 < iters) {
            proc(u1, it + 1);
            s1 = loadsrc((it + 5) * 4); u1 = gather(s1);
        }
        if (it + 2 < iters) {
            proc(u2, it + 2);
            s2 = loadsrc((it + 6) * 4); u2 = gather(s2);
        }
        if (it + 3 < iters) {
            proc(u3, it + 3);
            s3 = loadsrc((it + 7) * 4); u3 = gather(s3);
        }
    }

    // merge the 4 edge slots (lanes +-16, +-32 hold same cols)
    #pragma unroll
    for (int c = 0; c < 8; ++c) {
        acc[c] += __shfl_xor(acc[c], 16, 64);
        acc[c] += __shfl_xor(acc[c], 32, 64);
    }
    den += __shfl_xor(den, 16, 64);
    den += __shfl_xor(den, 32, 64);

    float rd = 1.0f / (den + 1e-16f);
    float sk[8];
    unpack8(*reinterpret_cast<const uint4*>(sk_b + (size_t)node * 128 + cb), sk);
    float4 w0 = *reinterpret_cast<const float4*>(Wo + cb);
    float4 w1 = *reinterpret_cast<const float4*>(Wo + cb + 4);
    float wv[8] = {w0.x, w0.y, w0.z, w0.w, w1.x, w1.y, w1.z, w1.w};
    float s = 0.0f;
    #pragma unroll
    for (int c = 0; c < 8; ++c) {
        float gg = fmaf(acc[c], rd, sk[c]);
        float el = gg > 0.0f ? gg : (exp2f(gg * LOG2E) - 1.0f);  // elu
        s = fmaf(el, wv[c], s);
    }
    s += __shfl_xor(s, 1, 64);
    s += __shfl_xor(s, 2, 64);
    s += __shfl_xor(s, 4, 64);
    s += __shfl_xor(s, 8, 64);
    if (lane == 0) {
        float z = s + bo[0];
        out[node] = 1.0f / (1.0f + exp2f(-z * LOG2E));
    }
}

// ---------------------------------------------------------------------------
extern "C" void kernel_launch(void* const* d_in, const int* in_sizes, int n_in,
                              void* d_out, int out_size, void* d_ws, size_t ws_size,
                              hipStream_t stream) {
    const float* x   = (const float*)d_in[0];
    const float* tf  = (const float*)d_in[1];
    const int*   ei  = (const int*)  d_in[2];
    const float* Wl  = (const float*)d_in[3];
    const float* Wr  = (const float*)d_in[4];
    const float* att = (const float*)d_in[5];
    const float* bg  = (const float*)d_in[6];
    const float* Ws  = (const float*)d_in[7];
    const float* bs  = (const float*)d_in[8];
    const float* Wo  = (const float*)d_in[9];
    const float* bo  = (const float*)d_in[10];
    float* out = (float*)d_out;

    const int N = in_sizes[0] / 126;
    const int E = in_sizes[2] / 2;

    char* ws = (char*)d_ws;
    unsigned short* Wt   = (unsigned short*)ws; ws += (size_t)384 * 128 * 2;
    unsigned short* xl_b = (unsigned short*)ws; ws += (size_t)N * 128 * 2;
    unsigned short* xr_b = (unsigned short*)ws; ws += (size_t)N * 128 * 2;
    unsigned short* sk_b = (unsigned short*)ws; ws += (size_t)N * 128 * 2;
    int* counts = (int*)ws; ws += (size_t)N * 4;
    int* dense  = (int*)ws; ws += (size_t)N * MAXDEG * 4;   // ~25.6 MB, no zeroing

    // 1: zero counts (graph-capturable) + weight pack
    hipMemsetAsync(counts, 0, (size_t)N * 4, stream);
    hipLaunchKernelGGL(kA_prep, dim3(192), dim3(256), 0, stream, Wl, Wr, Ws, Wt);
    // 2: dense-slot CSR build (atomic-bound) fused with node GEMM (overlap)
    const int GB = (N + 31) / 32;
    hipLaunchKernelGGL(kB_build_gemm, dim3(KB_HB + GB), dim3(256), 0, stream,
                       ei, E, counts, dense, x, tf, Wt, bg, bs,
                       xl_b, xr_b, sk_b, N);
    // 3: segment-reduce + finalize (register-resident 4-deep gather ring)
    hipLaunchKernelGGL(k2_aggfin, dim3((N + 3) / 4), dim3(256), 0, stream,
                       counts, dense, xl_b, xr_b, sk_b, att, Wo, bo, out, N);
}